// Round 5
// baseline (283.219 us; speedup 1.0000x reference)
//
#include <hip/hip_runtime.h>
#include <hip/hip_fp16.h>

// ============ prep kernels ============

__global__ __launch_bounds__(256) void k_zero(int* __restrict__ cnt,
                                              int* __restrict__ rpx, int n) {
    int i = blockIdx.x * 256 + threadIdx.x;
    if (i < n) cnt[i] = 0;
    if (i == 0) rpx[0] = 0;
}

// ============ FUSED: gemm1 (LDS-free) || count+rank ============
// Blocks [0, gemm_blocks): H[N,64] = fp16(x[N,128] @ W[128,64])  (no dinv yet).
//   Thread (tx,ty) of 256 computes rows ty*4..+3, cols tx*4..+3.
//   x loads: 4 unique 16B addrs per instr (broadcast over tx) - cheap.
//   W loads: 16 unique 16B per instr, reused by all ty/waves via L1 (32KB).
// Blocks [gemm_blocks, ...): rank[i] = atomicAdd(&cnt[dst[i]], 1).
//   Latency-bound scattered atomics hide under the gemm's VALU work.

__global__ __launch_bounds__(256) void k_gemm1_count(
        const float* __restrict__ x, const float* __restrict__ W,
        __half* __restrict__ H,
        const int* __restrict__ dst, int* __restrict__ cnt,
        int* __restrict__ rank, int gemm_blocks, int n, int e) {
    int bid = blockIdx.x;
    if (bid >= gemm_blocks) {
        int i = (bid - gemm_blocks) * 256 + threadIdx.x;
        if (i < e) rank[i] = atomicAdd(&cnt[dst[i]], 1);
        return;
    }

    const int t = threadIdx.x, tx = t & 15, ty = t >> 4;
    const int row0 = bid * 64;

    float acc[4][4];
#pragma unroll
    for (int r = 0; r < 4; ++r)
#pragma unroll
        for (int c = 0; c < 4; ++c) acc[r][c] = 0.f;

    for (int k = 0; k < 128; k += 4) {
        float4 wv[4];
#pragma unroll
        for (int kk = 0; kk < 4; ++kk)
            wv[kk] = *(const float4*)(W + (size_t)(k + kk) * 64 + tx * 4);
#pragma unroll
        for (int r = 0; r < 4; ++r) {
            int gr = row0 + ty * 4 + r;
            float4 xv = (gr < n) ? *(const float4*)(x + (size_t)gr * 128 + k)
                                 : make_float4(0.f, 0.f, 0.f, 0.f);
            float xk[4] = {xv.x, xv.y, xv.z, xv.w};
#pragma unroll
            for (int kk = 0; kk < 4; ++kk) {
                acc[r][0] = fmaf(xk[kk], wv[kk].x, acc[r][0]);
                acc[r][1] = fmaf(xk[kk], wv[kk].y, acc[r][1]);
                acc[r][2] = fmaf(xk[kk], wv[kk].z, acc[r][2]);
                acc[r][3] = fmaf(xk[kk], wv[kk].w, acc[r][3]);
            }
        }
    }

#pragma unroll
    for (int r = 0; r < 4; ++r) {
        int gr = row0 + ty * 4 + r;
        if (gr >= n) continue;
        union { __half2 h2[2]; uint2 u2; } pk;
        pk.h2[0] = __floats2half2_rn(acc[r][0], acc[r][1]);
        pk.h2[1] = __floats2half2_rn(acc[r][2], acc[r][3]);
        *(uint2*)(H + (size_t)gr * 64 + tx * 4) = pk.u2;
    }
}

// ============ scans (rpx inclusive from index 1; dinv) ============

__global__ __launch_bounds__(1024) void k_scan1(const int* __restrict__ cnt,
                                                int* __restrict__ rpx,
                                                int* __restrict__ bsum,
                                                float* __restrict__ dinv, int n) {
    __shared__ int sm[1024];
    int t = threadIdx.x;
    int i = blockIdx.x * 1024 + t;
    int v = (i < n) ? cnt[i] : 0;
    sm[t] = v;
    __syncthreads();
    for (int off = 1; off < 1024; off <<= 1) {
        int add = (t >= off) ? sm[t - off] : 0;
        __syncthreads();
        sm[t] += add;
        __syncthreads();
    }
    if (i < n) {
        rpx[i + 1] = sm[t];
        dinv[i]    = rsqrtf(1.0f + (float)v);
    }
    if (t == 1023) bsum[blockIdx.x] = sm[1023];
}

__global__ __launch_bounds__(1024) void k_scan2(int* __restrict__ bsum, int nb) {
    __shared__ int sm[1024];
    int t = threadIdx.x;
    int v = (t < nb) ? bsum[t] : 0;
    sm[t] = v;
    __syncthreads();
    for (int off = 1; off < 1024; off <<= 1) {
        int add = (t >= off) ? sm[t - off] : 0;
        __syncthreads();
        sm[t] += add;
        __syncthreads();
    }
    if (t < nb) bsum[t] = sm[t] - v;
}

__global__ __launch_bounds__(1024) void k_scan3(int* __restrict__ rpx,
                                                const int* __restrict__ bsum, int n) {
    int i = blockIdx.x * 1024 + threadIdx.x;
    if (i < n) rpx[i + 1] += bsum[blockIdx.x];
}

// ============ FUSED: fill (atomic-free) || hp *= dinv[row] ============

union Pk8 { float4 f4; __half2 h2[4]; };

__global__ __launch_bounds__(256) void k_fill_scale(
        const int* __restrict__ src, const int* __restrict__ dst,
        const int* __restrict__ rank, const int* __restrict__ rpx,
        int* __restrict__ csr, int e,
        __half* __restrict__ hp, const float* __restrict__ dinv,
        int fill_blocks, int n) {
    int bid = blockIdx.x;
    if (bid < fill_blocks) {
        int i = bid * 256 + threadIdx.x;
        if (i < e) csr[rpx[dst[i]] + rank[i]] = src[i];
        return;
    }
    // scale: one float4 (8 halves) per thread; node = i/8 (64 cols = 8 chunks)
    int i = (bid - fill_blocks) * 256 + threadIdx.x;
    if (i < n * 8) {
        int node = i >> 3;
        float di = dinv[node];
        Pk8 u;
        u.f4 = ((const float4*)hp)[i];
#pragma unroll
        for (int j = 0; j < 4; ++j) {
            float2 tt = __half22float2(u.h2[j]);
            u.h2[j] = __floats2half2_rn(tt.x * di, tt.y * di);
        }
        ((float4*)hp)[i] = u.f4;
    }
}

// ============ gather-side aggregation (fp16 rows, f32 accumulate) ============

__device__ inline void addrow(float acc[8], float4 v) {
    Pk8 u; u.f4 = v;
#pragma unroll
    for (int j = 0; j < 4; ++j) {
        float2 t = __half22float2(u.h2[j]);
        acc[2 * j]     += t.x;
        acc[2 * j + 1] += t.y;
    }
}

template<int LOGF>
__global__ __launch_bounds__(256) void k_aggregate(const int* __restrict__ rpx,
                                                   const int* __restrict__ csr,
                                                   const __half* __restrict__ hp,
                                                   const float* __restrict__ dinv,
                                                   const float* __restrict__ bias,
                                                   float* __restrict__ out, int n) {
    constexpr int F   = 1 << LOGF;
    constexpr int TPN = F / 8;
    int gid  = blockIdx.x * 256 + threadIdx.x;
    int node = gid / TPN;
    int q    = gid % TPN;
    if (node >= n) return;

    const float4* hp4 = (const float4*)hp;
    int start = rpx[node], end = rpx[node + 1];

    float acc[8];
#pragma unroll
    for (int j = 0; j < 8; ++j) acc[j] = 0.f;
    addrow(acc, hp4[(size_t)node * TPN + q]);   // self-loop

    int p = start;
    for (; p + 8 <= end; p += 8) {
        int s[8];
#pragma unroll
        for (int j = 0; j < 8; ++j) s[j] = csr[p + j];
        float4 v[8];
#pragma unroll
        for (int j = 0; j < 8; ++j) v[j] = hp4[(size_t)s[j] * TPN + q];
#pragma unroll
        for (int j = 0; j < 8; ++j) addrow(acc, v[j]);
    }
    for (; p + 2 <= end; p += 2) {
        int s0 = csr[p], s1 = csr[p + 1];
        float4 v0 = hp4[(size_t)s0 * TPN + q];
        float4 v1 = hp4[(size_t)s1 * TPN + q];
        addrow(acc, v0);
        addrow(acc, v1);
    }
    if (p < end)
        addrow(acc, hp4[(size_t)csr[p] * TPN + q]);

    float di = dinv[node];
    float4 b0 = ((const float4*)bias)[q * 2];
    float4 b1 = ((const float4*)bias)[q * 2 + 1];
    float4 r0, r1;
    r0.x = fmaf(acc[0], di, b0.x); r0.y = fmaf(acc[1], di, b0.y);
    r0.z = fmaf(acc[2], di, b0.z); r0.w = fmaf(acc[3], di, b0.w);
    r1.x = fmaf(acc[4], di, b1.x); r1.y = fmaf(acc[5], di, b1.y);
    r1.z = fmaf(acc[6], di, b1.z); r1.w = fmaf(acc[7], di, b1.w);
    float4* o4 = (float4*)out;
    o4[(size_t)node * (F / 4) + q * 2]     = r0;
    o4[(size_t)node * (F / 4) + q * 2 + 1] = r1;
}

// ============ GEMM2 (LDS-staged): hp2 = fp16( relu(agg1)@W2 * dinv ) ============

template<int K, int CPT, bool RELU_IN>
__global__ __launch_bounds__(256) void k_gemm(const float* __restrict__ A,
                                              const float* __restrict__ W,
                                              const float* __restrict__ dinv,
                                              __half* __restrict__ H, int n) {
    constexpr int OUT  = 16 * CPT;
    constexpr int ROWS = 64;
    constexpr int KS   = K + 4;
    __shared__ __align__(16) float xs[ROWS * KS];
    __shared__ __align__(16) float wsh[K * OUT];

    const int t    = threadIdx.x;
    const int row0 = blockIdx.x * ROWS;

    for (int i = t; i < K * OUT / 4; i += 256)
        ((float4*)wsh)[i] = ((const float4*)W)[i];

    constexpr int RF4 = K / 4;
    for (int i = t; i < ROWS * RF4; i += 256) {
        int r = i / RF4, c4 = i - r * RF4;
        float4 v = make_float4(0.f, 0.f, 0.f, 0.f);
        int gr = row0 + r;
        if (gr < n) {
            v = ((const float4*)(A + (size_t)gr * K))[c4];
            if (RELU_IN) {
                v.x = fmaxf(v.x, 0.f); v.y = fmaxf(v.y, 0.f);
                v.z = fmaxf(v.z, 0.f); v.w = fmaxf(v.w, 0.f);
            }
        }
        *(float4*)(xs + r * KS + c4 * 4) = v;
    }
    __syncthreads();

    const int tx = t & 15, ty = t >> 4;
    float acc[4][CPT];
#pragma unroll
    for (int i = 0; i < 4; ++i)
#pragma unroll
        for (int c = 0; c < CPT; ++c) acc[i][c] = 0.f;

    for (int k = 0; k < K; k += 4) {
        float xr[4][4];
#pragma unroll
        for (int i = 0; i < 4; ++i) {
            float4 xv = *(const float4*)(xs + (ty * 4 + i) * KS + k);
            xr[i][0] = xv.x; xr[i][1] = xv.y; xr[i][2] = xv.z; xr[i][3] = xv.w;
        }
#pragma unroll
        for (int kk = 0; kk < 4; ++kk) {
            float wv[CPT];
            if constexpr (CPT == 4) {
                float4 w4 = *(const float4*)(wsh + (k + kk) * OUT + tx * 4);
                wv[0] = w4.x; wv[1] = w4.y; wv[2] = w4.z; wv[3] = w4.w;
            } else {
                float2 w2 = *(const float2*)(wsh + (k + kk) * OUT + tx * 2);
                wv[0] = w2.x; wv[1] = w2.y;
            }
#pragma unroll
            for (int i = 0; i < 4; ++i)
#pragma unroll
                for (int c = 0; c < CPT; ++c)
                    acc[i][c] = fmaf(xr[i][kk], wv[c], acc[i][c]);
        }
    }

#pragma unroll
    for (int i = 0; i < 4; ++i) {
        int gr = row0 + ty * 4 + i;
        if (gr >= n) continue;
        float di = dinv[gr];
        if constexpr (CPT == 4) {
            union { __half2 h2[2]; uint2 u2; } pk;
            pk.h2[0] = __floats2half2_rn(acc[i][0] * di, acc[i][1] * di);
            pk.h2[1] = __floats2half2_rn(acc[i][2] * di, acc[i][3] * di);
            *(uint2*)(H + (size_t)gr * OUT + tx * 4) = pk.u2;
        } else {
            *(__half2*)(H + (size_t)gr * OUT + tx * 2) =
                __floats2half2_rn(acc[i][0] * di, acc[i][1] * di);
        }
    }
}

// ============ launch ============
// ws: cnt[N] | rpx[N+1] | csr[E] | dinv[N] | hp[64N halves] | agg1[64N f32] | bsum
// rank[E] overlays agg1 (dead before agg1 is first written).

extern "C" void kernel_launch(void* const* d_in, const int* in_sizes, int n_in,
                              void* d_out, int out_size, void* d_ws, size_t ws_size,
                              hipStream_t stream) {
    const float* x  = (const float*)d_in[0];
    const float* W1 = (const float*)d_in[1];
    const float* b1 = (const float*)d_in[2];
    const float* W2 = (const float*)d_in[3];
    const float* b2 = (const float*)d_in[4];
    const int*   ei = (const int*)d_in[5];

    const int N = in_sizes[0] / 128;
    const int E = in_sizes[5] / 2;
    const int* src = ei;
    const int* dst = ei + E;

    char* w = (char*)d_ws;
    int*    cnt  = (int*)w;                    w += (size_t)N * 4;
    int*    rpx  = (int*)w;                    w += (size_t)(N + 1) * 4 + 4;
    int*    csr  = (int*)w;                    w += (size_t)E * 4;
    float*  dinv = (float*)w;                  w += (size_t)N * 4;
    __half* hp   = (__half*)w;                 w += (size_t)N * 64 * 2;
    float*  agg1 = (float*)w;                  w += (size_t)N * 64 * 4;
    int*    bsum = (int*)w;                    w += 1024 * 4;
    int*    rank = (int*)agg1;                 // overlay
    float*  out  = (float*)d_out;

    const int nb_n = (N + 255) / 256;
    const int nb_e = (E + 255) / 256;
    const int nb_s = (N + 1023) / 1024;
    const int gb1  = (N + 63) / 64;            // gemm1 blocks
    const int sb   = (N * 8 + 255) / 256;      // scale blocks

    k_zero<<<nb_n, 256, 0, stream>>>(cnt, rpx, N);

    // gemm1 (h = x@W1, fp16, unscaled) overlapped with count+rank
    k_gemm1_count<<<gb1 + nb_e, 256, 0, stream>>>(x, W1, hp, dst, cnt, rank,
                                                  gb1, N, E);

    k_scan1<<<nb_s, 1024, 0, stream>>>(cnt, rpx, bsum, dinv, N);
    k_scan2<<<1,    1024, 0, stream>>>(bsum, nb_s);
    k_scan3<<<nb_s, 1024, 0, stream>>>(rpx, bsum, N);

    // fill CSR overlapped with hp *= dinv[row]
    k_fill_scale<<<nb_e + sb, 256, 0, stream>>>(src, dst, rank, rpx, csr, E,
                                                hp, dinv, nb_e, N);

    // layer 1 aggregate: agg1 = (self + gathered) * dinv + b1
    k_aggregate<6><<<(N * 8 + 255) / 256, 256, 0, stream>>>(rpx, csr, hp, dinv, b1, agg1, N);

    // layer 2: hp2 = fp16(relu(agg1)@W2 * dinv) ; out = gather-agg + b2
    k_gemm<64, 2, true><<<(N + 63) / 64, 256, 0, stream>>>(agg1, W2, dinv, hp, N);
    k_aggregate<5><<<(N * 4 + 255) / 256, 256, 0, stream>>>(rpx, csr, hp, dinv, b2, out, N);
}

// Round 6
// 259.046 us; speedup vs baseline: 1.0933x; 1.0933x over previous
//
#include <hip/hip_runtime.h>
#include <hip/hip_fp16.h>

// ============ count+rank: 8 independent atomics in flight per thread ============
// Latency-bound scattered atomic-with-return: throughput = in-flight / latency.
// 8 returns land in separate VGPRs; rank stored as int4 pairs afterwards.

__global__ __launch_bounds__(256) void k_count(const int* __restrict__ dst,
                                               int* __restrict__ cnt,
                                               int* __restrict__ rank, int e) {
    int base = (blockIdx.x * 256 + threadIdx.x) * 8;
    if (base + 8 <= e) {
        int4 d0 = *(const int4*)(dst + base);
        int4 d1 = *(const int4*)(dst + base + 4);
        int4 r0, r1;
        r0.x = atomicAdd(&cnt[d0.x], 1);
        r0.y = atomicAdd(&cnt[d0.y], 1);
        r0.z = atomicAdd(&cnt[d0.z], 1);
        r0.w = atomicAdd(&cnt[d0.w], 1);
        r1.x = atomicAdd(&cnt[d1.x], 1);
        r1.y = atomicAdd(&cnt[d1.y], 1);
        r1.z = atomicAdd(&cnt[d1.z], 1);
        r1.w = atomicAdd(&cnt[d1.w], 1);
        *(int4*)(rank + base)     = r0;
        *(int4*)(rank + base + 4) = r1;
    } else {
        for (int i = base; i < e; ++i)
            rank[i] = atomicAdd(&cnt[dst[i]], 1);
    }
}

// ============ scans (rpx[0]=0 here; rpx[i+1]=inclusive; dinv) ============

__global__ __launch_bounds__(1024) void k_scan1(const int* __restrict__ cnt,
                                                int* __restrict__ rpx,
                                                int* __restrict__ bsum,
                                                float* __restrict__ dinv, int n) {
    __shared__ int sm[1024];
    int t = threadIdx.x;
    int i = blockIdx.x * 1024 + t;
    int v = (i < n) ? cnt[i] : 0;
    sm[t] = v;
    __syncthreads();
    for (int off = 1; off < 1024; off <<= 1) {
        int add = (t >= off) ? sm[t - off] : 0;
        __syncthreads();
        sm[t] += add;
        __syncthreads();
    }
    if (i < n) {
        rpx[i + 1] = sm[t];
        dinv[i]    = rsqrtf(1.0f + (float)v);
    }
    if (i == 0) rpx[0] = 0;
    if (t == 1023) bsum[blockIdx.x] = sm[1023];
}

__global__ __launch_bounds__(1024) void k_scan2(int* __restrict__ bsum, int nb) {
    __shared__ int sm[1024];
    int t = threadIdx.x;
    int v = (t < nb) ? bsum[t] : 0;
    sm[t] = v;
    __syncthreads();
    for (int off = 1; off < 1024; off <<= 1) {
        int add = (t >= off) ? sm[t - off] : 0;
        __syncthreads();
        sm[t] += add;
        __syncthreads();
    }
    if (t < nb) bsum[t] = sm[t] - v;
}

__global__ __launch_bounds__(1024) void k_scan3(int* __restrict__ rpx,
                                                const int* __restrict__ bsum, int n) {
    int i = blockIdx.x * 1024 + threadIdx.x;
    if (i < n) rpx[i + 1] += bsum[blockIdx.x];
}

// ============ fill: atomic-free, 4 edges per thread (4 stores in flight) ============

__global__ __launch_bounds__(256) void k_fill(const int* __restrict__ src,
                                              const int* __restrict__ dst,
                                              const int* __restrict__ rank,
                                              const int* __restrict__ rpx,
                                              int* __restrict__ csr, int e) {
    int base = (blockIdx.x * 256 + threadIdx.x) * 4;
    if (base + 4 <= e) {
        int4 s = *(const int4*)(src + base);
        int4 d = *(const int4*)(dst + base);
        int4 r = *(const int4*)(rank + base);
        int p0 = rpx[d.x], p1 = rpx[d.y], p2 = rpx[d.z], p3 = rpx[d.w];
        csr[p0 + r.x] = s.x;
        csr[p1 + r.y] = s.y;
        csr[p2 + r.z] = s.z;
        csr[p3 + r.w] = s.w;
    } else {
        for (int i = base; i < e; ++i)
            csr[rpx[dst[i]] + rank[i]] = src[i];
    }
}

// ============ gather-side aggregation (fp16 rows, f32 accumulate) ============

union Pk8 { float4 f4; __half2 h2[4]; };

__device__ inline void addrow(float acc[8], float4 v) {
    Pk8 u; u.f4 = v;
#pragma unroll
    for (int j = 0; j < 4; ++j) {
        float2 t = __half22float2(u.h2[j]);
        acc[2 * j]     += t.x;
        acc[2 * j + 1] += t.y;
    }
}

template<int LOGF>
__global__ __launch_bounds__(256) void k_aggregate(const int* __restrict__ rpx,
                                                   const int* __restrict__ csr,
                                                   const __half* __restrict__ hp,
                                                   const float* __restrict__ dinv,
                                                   const float* __restrict__ bias,
                                                   float* __restrict__ out, int n) {
    constexpr int F   = 1 << LOGF;
    constexpr int TPN = F / 8;
    int gid  = blockIdx.x * 256 + threadIdx.x;
    int node = gid / TPN;
    int q    = gid % TPN;
    if (node >= n) return;

    const float4* hp4 = (const float4*)hp;
    int start = rpx[node], end = rpx[node + 1];

    float acc[8];
#pragma unroll
    for (int j = 0; j < 8; ++j) acc[j] = 0.f;
    addrow(acc, hp4[(size_t)node * TPN + q]);   // self-loop

    int p = start;
    for (; p + 8 <= end; p += 8) {
        int s[8];
#pragma unroll
        for (int j = 0; j < 8; ++j) s[j] = csr[p + j];
        float4 v[8];
#pragma unroll
        for (int j = 0; j < 8; ++j) v[j] = hp4[(size_t)s[j] * TPN + q];
#pragma unroll
        for (int j = 0; j < 8; ++j) addrow(acc, v[j]);
    }
    for (; p + 2 <= end; p += 2) {
        int s0 = csr[p], s1 = csr[p + 1];
        float4 v0 = hp4[(size_t)s0 * TPN + q];
        float4 v1 = hp4[(size_t)s1 * TPN + q];
        addrow(acc, v0);
        addrow(acc, v1);
    }
    if (p < end)
        addrow(acc, hp4[(size_t)csr[p] * TPN + q]);

    float di = dinv[node];
    float4 b0 = ((const float4*)bias)[q * 2];
    float4 b1 = ((const float4*)bias)[q * 2 + 1];
    float4 r0, r1;
    r0.x = fmaf(acc[0], di, b0.x); r0.y = fmaf(acc[1], di, b0.y);
    r0.z = fmaf(acc[2], di, b0.z); r0.w = fmaf(acc[3], di, b0.w);
    r1.x = fmaf(acc[4], di, b1.x); r1.y = fmaf(acc[5], di, b1.y);
    r1.z = fmaf(acc[6], di, b1.z); r1.w = fmaf(acc[7], di, b1.w);
    float4* o4 = (float4*)out;
    o4[(size_t)node * (F / 4) + q * 2]     = r0;
    o4[(size_t)node * (F / 4) + q * 2 + 1] = r1;
}

// ============ GEMM (LDS-staged): H' = fp16( (A@W) * dinv[row] ) ============

template<int K, int CPT, bool RELU_IN>
__global__ __launch_bounds__(256) void k_gemm(const float* __restrict__ A,
                                              const float* __restrict__ W,
                                              const float* __restrict__ dinv,
                                              __half* __restrict__ H, int n) {
    constexpr int OUT  = 16 * CPT;
    constexpr int ROWS = 64;
    constexpr int KS   = K + 4;
    __shared__ __align__(16) float xs[ROWS * KS];
    __shared__ __align__(16) float wsh[K * OUT];

    const int t    = threadIdx.x;
    const int row0 = blockIdx.x * ROWS;

    for (int i = t; i < K * OUT / 4; i += 256)
        ((float4*)wsh)[i] = ((const float4*)W)[i];

    constexpr int RF4 = K / 4;
    for (int i = t; i < ROWS * RF4; i += 256) {
        int r = i / RF4, c4 = i - r * RF4;
        float4 v = make_float4(0.f, 0.f, 0.f, 0.f);
        int gr = row0 + r;
        if (gr < n) {
            v = ((const float4*)(A + (size_t)gr * K))[c4];
            if (RELU_IN) {
                v.x = fmaxf(v.x, 0.f); v.y = fmaxf(v.y, 0.f);
                v.z = fmaxf(v.z, 0.f); v.w = fmaxf(v.w, 0.f);
            }
        }
        *(float4*)(xs + r * KS + c4 * 4) = v;
    }
    __syncthreads();

    const int tx = t & 15, ty = t >> 4;
    float acc[4][CPT];
#pragma unroll
    for (int i = 0; i < 4; ++i)
#pragma unroll
        for (int c = 0; c < CPT; ++c) acc[i][c] = 0.f;

    for (int k = 0; k < K; k += 4) {
        float xr[4][4];
#pragma unroll
        for (int i = 0; i < 4; ++i) {
            float4 xv = *(const float4*)(xs + (ty * 4 + i) * KS + k);
            xr[i][0] = xv.x; xr[i][1] = xv.y; xr[i][2] = xv.z; xr[i][3] = xv.w;
        }
#pragma unroll
        for (int kk = 0; kk < 4; ++kk) {
            float wv[CPT];
            if constexpr (CPT == 4) {
                float4 w4 = *(const float4*)(wsh + (k + kk) * OUT + tx * 4);
                wv[0] = w4.x; wv[1] = w4.y; wv[2] = w4.z; wv[3] = w4.w;
            } else {
                float2 w2 = *(const float2*)(wsh + (k + kk) * OUT + tx * 2);
                wv[0] = w2.x; wv[1] = w2.y;
            }
#pragma unroll
            for (int i = 0; i < 4; ++i)
#pragma unroll
                for (int c = 0; c < CPT; ++c)
                    acc[i][c] = fmaf(xr[i][kk], wv[c], acc[i][c]);
        }
    }

#pragma unroll
    for (int i = 0; i < 4; ++i) {
        int gr = row0 + ty * 4 + i;
        if (gr >= n) continue;
        float di = dinv[gr];
        if constexpr (CPT == 4) {
            union { __half2 h2[2]; uint2 u2; } pk;
            pk.h2[0] = __floats2half2_rn(acc[i][0] * di, acc[i][1] * di);
            pk.h2[1] = __floats2half2_rn(acc[i][2] * di, acc[i][3] * di);
            *(uint2*)(H + (size_t)gr * OUT + tx * 4) = pk.u2;
        } else {
            *(__half2*)(H + (size_t)gr * OUT + tx * 2) =
                __floats2half2_rn(acc[i][0] * di, acc[i][1] * di);
        }
    }
}

// ============ launch ============
// ws: cnt[N] | rpx[N+1] | csr[E] | dinv[N] | hp[64N halves] | agg1[64N f32] | bsum
// rank[E] overlays agg1 (dead before agg1 is first written).

extern "C" void kernel_launch(void* const* d_in, const int* in_sizes, int n_in,
                              void* d_out, int out_size, void* d_ws, size_t ws_size,
                              hipStream_t stream) {
    const float* x  = (const float*)d_in[0];
    const float* W1 = (const float*)d_in[1];
    const float* b1 = (const float*)d_in[2];
    const float* W2 = (const float*)d_in[3];
    const float* b2 = (const float*)d_in[4];
    const int*   ei = (const int*)d_in[5];

    const int N = in_sizes[0] / 128;
    const int E = in_sizes[5] / 2;
    const int* src = ei;
    const int* dst = ei + E;

    char* w = (char*)d_ws;
    int*    cnt  = (int*)w;                    w += (size_t)N * 4;
    int*    rpx  = (int*)w;                    w += (size_t)(N + 1) * 4 + 4;
    int*    csr  = (int*)w;                    w += (size_t)E * 4;
    float*  dinv = (float*)w;                  w += (size_t)N * 4;
    __half* hp   = (__half*)w;                 w += (size_t)N * 64 * 2;
    float*  agg1 = (float*)w;                  w += (size_t)N * 64 * 4;
    int*    bsum = (int*)w;                    w += 1024 * 4;
    int*    rank = (int*)agg1;                 // overlay: dead before agg1 write
    float*  out  = (float*)d_out;

    const int nb_e8 = (E / 8 + 256) / 256;     // count blocks (8 edges/thread)
    const int nb_e4 = (E / 4 + 256) / 256;     // fill blocks (4 edges/thread)
    const int nb_s  = (N + 1023) / 1024;

    hipMemsetAsync(cnt, 0, (size_t)N * 4, stream);
    k_count<<<nb_e8, 256, 0, stream>>>(dst, cnt, rank, E);
    k_scan1<<<nb_s, 1024, 0, stream>>>(cnt, rpx, bsum, dinv, N);
    k_scan2<<<1,    1024, 0, stream>>>(bsum, nb_s);
    k_scan3<<<nb_s, 1024, 0, stream>>>(rpx, bsum, N);
    k_fill <<<nb_e4, 256, 0, stream>>>(src, dst, rank, rpx, csr, E);

    // layer 1: hp = fp16((x@W1)*dinv) ; agg1 = gather-agg + b1 (f32)
    k_gemm<128, 4, false><<<(N + 63) / 64, 256, 0, stream>>>(x, W1, dinv, hp, N);
    k_aggregate<6><<<(N * 8 + 255) / 256, 256, 0, stream>>>(rpx, csr, hp, dinv, b1, agg1, N);

    // layer 2: hp2 = fp16(relu(agg1)@W2 * dinv) ; out = gather-agg + b2 (f32)
    k_gemm<64, 2, true><<<(N + 63) / 64, 256, 0, stream>>>(agg1, W2, dinv, hp, N);
    k_aggregate<5><<<(N * 4 + 255) / 256, 256, 0, stream>>>(rpx, csr, hp, dinv, b2, out, N);
}